// Round 9
// baseline (542.740 us; speedup 1.0000x reference)
//
#include <hip/hip_runtime.h>
#include <hip/hip_bf16.h>
#include <math.h>

// Problem constants
#define Bb 2
#define Mm 2048
#define Nn 2048
#define Ff 8
#define Gg 60
#define Kk 32
#define Dd 32
#define Hh 4
#define DHh 8

// ---------------------------------------------------------------------------
// Kernel 1: transpose target (B,D,N,1) -> targetT (B,N,D) for coalesced dots
// ---------------------------------------------------------------------------
__global__ __launch_bounds__(256) void transpose_kernel(
    const float* __restrict__ target, float* __restrict__ tT)
{
    __shared__ float tile[32][33];
    int blk = blockIdx.x;          // 0..127  (B * N/32)
    int b = blk >> 6;
    int n0 = (blk & 63) << 5;
    int t = threadIdx.x;
    int col = t & 31;
    int rowb = t >> 5;             // 0..7
#pragma unroll
    for (int i = 0; i < 4; ++i) {
        int d = rowb + i * 8;
        tile[d][col] = target[(b * 32 + d) * 2048 + n0 + col];
    }
    __syncthreads();
#pragma unroll
    for (int i = 0; i < 4; ++i) {
        int r = rowb + i * 8;      // local n
        tT[(b * 2048 + n0 + r) * 32 + col] = tile[col][r];
    }
}

// ---------------------------------------------------------------------------
// Kernel 2 (v4): fused score + top-32.  8 waves (512 thr) per block, each
// wave owns ONE m-row.  tT staged in 64-n chunks through double-buffered
// LDS via global_load_lds (1 op/wave/chunk, vmcnt(1) steady state).
// v4 changes vs v3 (which was VALU-issue-bound, VALUBusy 69%):
//  - selection: 4 group-maxima over val[8g..8g+7]; removal recomputes ONE
//    group (masked 8-scan) instead of all 32 -> ~3x fewer selection ops.
//  - ds_read addresses hoisted: 8 offset VGPRs, buffer via +8192 immediate.
// Exact top-32, min-index tie-break preserved at every level.
// ---------------------------------------------------------------------------
__global__ __launch_bounds__(512, 4) void score_topk_kernel(
    const float* __restrict__ src, const float* __restrict__ tT,
    int* __restrict__ knn)
{
    __shared__ float4 tile[2][512];     // 2 x 8KB chunk buffers [row*8 + slot]
    __shared__ float s_sh[8][32];       // 8 source vectors for this block

    int blk = blockIdx.x;               // 512 blocks
    int b = blk >> 8;
    int m0 = (blk & 255) << 3;
    int t = threadIdx.x;                // 0..511
    int wave = t >> 6, lane = t & 63;

    // stage slot L = t; row r0 = L>>3 (0..63), swizzled col c0 = (L&7)^(r0&7)
    int r0 = t >> 3;
    int c0 = (t & 7) ^ (r0 & 7);

    const float4* tpan = (const float4*)(tT + b * 2048 * 32);  // 8 float4/row

    // ---- prologue: stage chunk 0 + load the 8 source vectors ----
    {
        const float4* gp = tpan + r0 * 8 + c0;       // chunk 0: n0 = 0
        __builtin_amdgcn_global_load_lds(
            (const __attribute__((address_space(1))) void*)gp,
            (__attribute__((address_space(3))) void*)&tile[0][wave * 64],
            16, 0, 0);
    }
    if (t < 256) {
        int d = t >> 3, mi = t & 7;
        s_sh[mi][d] = src[(b * 32 + d) * 2048 + m0 + mi];
    }
    __syncthreads();   // drains vmcnt(0): chunk 0 + s_sh ready

    float sr[32];
#pragma unroll
    for (int i = 0; i < 32; ++i) sr[i] = s_sh[wave][i];

    float val[32];
    // hoisted swizzled byte offsets into buffer 0 (buffer 1 = +8192 imm)
    const char* lds0 = (const char*)&tile[0][0];
    int offq[8];
#pragma unroll
    for (int q = 0; q < 8; ++q)
        offq[q] = (lane * 8 + (q ^ (lane & 7))) * 16;

    // ---- main loop: 32 chunks of 64 n ----
#pragma unroll
    for (int c = 0; c < 32; ++c) {
        int cur = c & 1;
        if (c < 31) {
            int n0 = (c + 1) << 6;
            const float4* gp = tpan + (n0 + r0) * 8 + c0;
            __builtin_amdgcn_global_load_lds(
                (const __attribute__((address_space(1))) void*)gp,
                (__attribute__((address_space(3))) void*)&tile[cur ^ 1][wave * 64],
                16, 0, 0);
            asm volatile("s_waitcnt vmcnt(1)" ::: "memory");  // chunk c landed
        } else {
            asm volatile("s_waitcnt vmcnt(0)" ::: "memory");
        }
        __builtin_amdgcn_s_barrier();     // all waves' chunk-c stores landed
        asm volatile("" ::: "memory");    // fence: no load hoisting above barrier

        float a0 = 0.f;
#pragma unroll
        for (int q = 0; q < 8; ++q) {
            float4 f = *(const float4*)(lds0 + (cur ? 8192 : 0) + offq[q]);
            a0 += f.x * sr[4 * q] + f.y * sr[4 * q + 1] +
                  f.z * sr[4 * q + 2] + f.w * sr[4 * q + 3];
        }
        val[c] = a0;
        asm volatile("s_waitcnt lgkmcnt(0)" ::: "memory");  // reads of buf done
        __builtin_amdgcn_s_barrier();     // before next stage overwrites buf
        asm volatile("" ::: "memory");
    }

    // ---- exact top-32 selection (scores val[j] for n = j*64 + lane) ----
    // two-level per-lane: 4 group maxima (groups of 8 j's); strict '>' keeps
    // min-j at every level; butterfly keeps min-n on value ties.
    unsigned mask = 0u;
    float gv0, gv1, gv2, gv3;
    int gj0, gj1, gj2, gj3;
#define REGRP(GV, GJ, BASE)                                                   \
    {                                                                         \
        GV = -INFINITY; GJ = 0x3FFFFF;                                        \
        _Pragma("unroll")                                                     \
        for (int jj = (BASE); jj < (BASE) + 8; ++jj)                          \
            if (!((mask >> jj) & 1u) && val[jj] > GV) { GV = val[jj]; GJ = jj; } \
    }
    REGRP(gv0, gj0, 0)
    REGRP(gv1, gj1, 8)
    REGRP(gv2, gj2, 16)
    REGRP(gv3, gj3, 24)

    int m = m0 + wave;
    int* kout = knn + (b * 2048 + m) * 32;
    for (int k = 0; k < 32; ++k) {
        float bv = gv0; int bj = gj0;
        if (gv1 > bv) { bv = gv1; bj = gj1; }
        if (gv2 > bv) { bv = gv2; bj = gj2; }
        if (gv3 > bv) { bv = gv3; bj = gj3; }
        float v = bv;
        int ni = lane + (bj << 6);
#pragma unroll
        for (int off = 32; off > 0; off >>= 1) {
            float ov = __shfl_xor(v, off);
            int oi = __shfl_xor(ni, off);
            if (ov > v || (ov == v && oi < ni)) { v = ov; ni = oi; }
        }
        if (lane == 0) kout[k] = ni;
        if ((ni & 63) == lane) {          // owner lane: remove, fix ONE group
            int jr = ni >> 6;
            mask |= 1u << jr;
            if (jr < 8)       REGRP(gv0, gj0, 0)
            else if (jr < 16) REGRP(gv1, gj1, 8)
            else if (jr < 24) REGRP(gv2, gj2, 16)
            else              REGRP(gv3, gj3, 24)
        }
    }
#undef REGRP
}

// ---------------------------------------------------------------------------
// Kernel 3: fused gather + QKV + attention + feat_attn + MLP layer 1.
// One block (256 thr) per (b,m). Head h owns channels d with d%4==h.
// ---------------------------------------------------------------------------
__global__ __launch_bounds__(256) void attn_kernel(
    const float* __restrict__ src, const float* __restrict__ featinv,
    const float* __restrict__ tT, const int* __restrict__ knn,
    const float* __restrict__ wq, const float* __restrict__ bq,
    const float* __restrict__ wk, const float* __restrict__ bk,
    const float* __restrict__ wv, const float* __restrict__ bv,
    const float* __restrict__ wm, const float* __restrict__ bm,
    const float* __restrict__ w1, const float* __restrict__ b1,
    float* __restrict__ fat, float* __restrict__ h1out)
{
    __shared__ float kf[32][33], kk[32][33], vv[32][33];
    __shared__ float wks[1024], wvs[1024];       // transposed: [i*32+o]
    __shared__ float s[32], qv[32], xv[32];
    __shared__ float scs[4][32], prob[4][32];
    __shared__ float cat[96];
    __shared__ int idx[32];

    int blk = blockIdx.x;
    int b = blk >> 11;
    int m = blk & 2047;
    int t = threadIdx.x;
    int d = t & 31, kn0 = t >> 5;

    if (t < 32) {
        s[t] = src[(b * 32 + t) * 2048 + m];
        idx[t] = knn[(b * 2048 + m) * 32 + t];
    }
#pragma unroll
    for (int r = 0; r < 4; ++r) {
        int w = t + 256 * r;
        wks[w] = wk[(w & 31) * 32 + (w >> 5)];   // wks[i*32+o] = wk[o][i]
        wvs[w] = wv[(w & 31) * 32 + (w >> 5)];
    }
    __syncthreads();

    // gather 32 neighbor features (coalesced 128B per neighbor)
#pragma unroll
    for (int i = 0; i < 4; ++i) {
        int kn = kn0 + i * 8;
        kf[kn][d] = tT[(b * 2048 + idx[kn]) * 32 + d];
    }
    if (t < 32) {
        float acc = bq[t];
#pragma unroll
        for (int i = 0; i < 32; ++i) acc += wq[t * 32 + i] * s[i];
        qv[t] = acc;
    }
    __syncthreads();

    // K,V projections: thread (o=d, kn = kn0+8i)
#pragma unroll
    for (int i = 0; i < 4; ++i) {
        int kn = kn0 + i * 8;
        float ak = bk[d], av = bv[d];
#pragma unroll
        for (int j = 0; j < 32; ++j) {
            float f = kf[kn][j];
            ak += wks[j * 32 + d] * f;
            av += wvs[j * 32 + d] * f;
        }
        kk[kn][d] = ak;
        vv[kn][d] = av;
    }
    __syncthreads();

    // attention scores: head h uses channels dh*4+h
    if (t < 128) {
        int kn = t >> 2, h = t & 3;
        float acc = 0.f;
#pragma unroll
        for (int dh = 0; dh < 8; ++dh) acc += qv[dh * 4 + h] * kk[kn][dh * 4 + h];
        scs[h][kn] = acc * 0.35355339059327373f;  // 1/sqrt(8)
    }
    __syncthreads();
    // wave-parallel softmax: t = h*32 + kn, shfl reductions within 32-lane groups
    if (t < 128) {
        int h = t >> 5, kn = t & 31;
        float sc = scs[h][kn];
        float mx = sc;
#pragma unroll
        for (int off = 16; off > 0; off >>= 1) mx = fmaxf(mx, __shfl_xor(mx, off));
        float e = expf(sc - mx);
        float sum = e;
#pragma unroll
        for (int off = 16; off > 0; off >>= 1) sum += __shfl_xor(sum, off);
        prob[h][kn] = e / sum;
    }
    __syncthreads();
    if (t < 32) {
        int h = t & 3;
        float acc = 0.f;
#pragma unroll
        for (int kn = 0; kn < 32; ++kn) acc += prob[h][kn] * vv[kn][t];
        xv[t] = acc;
    }
    __syncthreads();
    if (t < 32) {
        float acc = bm[t];
#pragma unroll
        for (int i = 0; i < 32; ++i) acc += wm[t * 32 + i] * xv[i];
        fat[(b * 32 + t) * 2048 + m] = acc;
        cat[t] = featinv[(b * 32 + t) * 2048 + m];
        cat[32 + t] = s[t];
        cat[64 + t] = acc;
    }
    __syncthreads();
    // MLP layer 1 (96 -> 64); instance-norm stats need global pass -> store
    if (t < 64) {
        float acc = b1[t];
#pragma unroll
        for (int i = 0; i < 96; ++i) acc += w1[t * 96 + i] * cat[i];
        h1out[(b * 64 + t) * 2048 + m] = acc;
    }
}

// ---------------------------------------------------------------------------
// Kernel 4: instance-norm stats per (b, channel) over M
// ---------------------------------------------------------------------------
__global__ __launch_bounds__(256) void stats_kernel(
    const float* __restrict__ h1, float* __restrict__ mu, float* __restrict__ rstd)
{
    __shared__ float rs[256], rq[256];
    int bc = blockIdx.x;
    int t = threadIdx.x;
    const float* row = h1 + bc * 2048;
    float sum = 0.f, sq = 0.f;
#pragma unroll
    for (int r = 0; r < 8; ++r) {
        float v = row[t + 256 * r];
        sum += v;
        sq += v * v;
    }
    rs[t] = sum; rq[t] = sq;
    __syncthreads();
    for (int off = 128; off > 0; off >>= 1) {
        if (t < off) { rs[t] += rs[t + off]; rq[t] += rq[t + off]; }
        __syncthreads();
    }
    if (t == 0) {
        float m_ = rs[0] * (1.f / 2048.f);
        float var = rq[0] * (1.f / 2048.f) - m_ * m_;
        mu[bc] = m_;
        rstd[bc] = rsqrtf(var + 1e-5f);
    }
}

// ---------------------------------------------------------------------------
// Kernel 5: norm + ReLU + (w2 @ h + wres @ cat) epilogue -> feat_out
// One block handles 8 m values; thread = (m-sub g, out channel o).
// ---------------------------------------------------------------------------
__global__ __launch_bounds__(256) void final_kernel(
    const float* __restrict__ src, const float* __restrict__ featinv,
    const float* __restrict__ fat, const float* __restrict__ h1,
    const float* __restrict__ mu, const float* __restrict__ rstd,
    const float* __restrict__ w2, const float* __restrict__ b2,
    const float* __restrict__ wres, const float* __restrict__ bres,
    float* __restrict__ out)
{
    __shared__ float hbuf[64][8];
    __shared__ float catbuf[96][8];
    __shared__ float w2s[2048];    // [c*32+o]
    __shared__ float wress[3072];  // [i*32+o]
    int blk = blockIdx.x;
    int b = blk >> 8;
    int m0 = (blk & 255) << 3;
    int t = threadIdx.x;
#pragma unroll
    for (int r = 0; r < 8; ++r) {
        int w = t + 256 * r;
        w2s[w] = w2[(w & 31) * 64 + (w >> 5)];
    }
#pragma unroll
    for (int r = 0; r < 12; ++r) {
        int w = t + 256 * r;
        wress[w] = wres[(w & 31) * 96 + (w >> 5)];
    }
#pragma unroll
    for (int r = 0; r < 2; ++r) {
        int i = t + 256 * r;
        int c = i >> 3, mm = i & 7;
        int bc = b * 64 + c;
        float v = h1[(b * 64 + c) * 2048 + m0 + mm];
        v = (v - mu[bc]) * rstd[bc];
        hbuf[c][mm] = fmaxf(v, 0.f);
    }
#pragma unroll
    for (int r = 0; r < 3; ++r) {
        int i = t + 256 * r;
        int c = i >> 3, mm = i & 7;
        float v;
        if (c < 32)      v = featinv[(b * 32 + c) * 2048 + m0 + mm];
        else if (c < 64) v = src[(b * 32 + (c - 32)) * 2048 + m0 + mm];
        else             v = fat[(b * 32 + (c - 64)) * 2048 + m0 + mm];
        catbuf[c][mm] = v;
    }
    __syncthreads();
    int o = t & 31, g = t >> 5;
    float acc = b2[o] + bres[o];
#pragma unroll
    for (int c = 0; c < 64; ++c) acc += w2s[c * 32 + o] * hbuf[c][g];
#pragma unroll
    for (int i = 0; i < 96; ++i) acc += wress[i * 32 + o] * catbuf[i][g];
    out[(b * 32 + o) * 2048 + m0 + g] = acc;
}

// ---------------------------------------------------------------------------
// Kernel 6 (v2): R_indicator. One block per (b,m).
// R[h2] = sum_{f,g} source_eqv[b,f,m,perms[g*60+h2]] * target_eqv[b,f,nn,g]
// LDS layouts transposed to [g][f] float4 pairs: inner gather is 4x
// ds_read_b128 instead of 16x scalar reads.
// ---------------------------------------------------------------------------
__global__ __launch_bounds__(256) void r_kernel(
    const float* __restrict__ source_eqv, const float* __restrict__ target_eqv,
    const int* __restrict__ perms, const int* __restrict__ knn,
    float* __restrict__ out)
{
    __shared__ float4 seT[60][2];   // [p][f/4]
    __shared__ float4 tkT[60][2];   // [g][f/4]
    __shared__ int pl[3600];
    __shared__ float part[4][60];
    int blk = blockIdx.x;
    int b = blk >> 11;
    int m = blk & 2047;
    int t = threadIdx.x;
    int nn = knn[(b * 2048 + m) * 32];   // top-1 index
#pragma unroll
    for (int r = 0; r < 2; ++r) {
        int i = t + 256 * r;
        if (i < 480) {
            int f = i / 60, g = i - f * 60;
            ((float*)&tkT[g][0])[f] = target_eqv[((b * 8 + f) * 2048 + nn) * 60 + g];
            ((float*)&seT[g][0])[f] = source_eqv[((b * 8 + f) * 2048 + m) * 60 + g];
        }
    }
#pragma unroll
    for (int r = 0; r < 15; ++r) {
        int i = t + 256 * r;
        if (i < 3600) pl[i] = perms[i];
    }
    __syncthreads();
    if (t < 240) {
        int h2 = t % 60, quarter = t / 60;
        float acc = 0.f;
        for (int g = quarter * 15; g < quarter * 15 + 15; ++g) {
            int p = pl[g * 60 + h2];
            float4 s0 = seT[p][0], s1 = seT[p][1];
            float4 k0 = tkT[g][0], k1 = tkT[g][1];
            acc += s0.x * k0.x + s0.y * k0.y + s0.z * k0.z + s0.w * k0.w
                 + s1.x * k1.x + s1.y * k1.y + s1.z * k1.z + s1.w * k1.w;
        }
        part[quarter][h2] = acc;
    }
    __syncthreads();
    if (t < 60)
        out[(b * 60 + t) * 2048 + m] =
            part[0][t] + part[1][t] + part[2][t] + part[3][t];
}

// ---------------------------------------------------------------------------
extern "C" void kernel_launch(void* const* d_in, const int* in_sizes, int n_in,
                              void* d_out, int out_size, void* d_ws, size_t ws_size,
                              hipStream_t stream)
{
    const float* source     = (const float*)d_in[0];
    const float* target     = (const float*)d_in[1];
    const float* source_eqv = (const float*)d_in[2];
    const float* target_eqv = (const float*)d_in[3];
    const float* featinv    = (const float*)d_in[4];
    const int*   perms      = (const int*)d_in[5];
    const float* wq = (const float*)d_in[6];   const float* bq = (const float*)d_in[7];
    const float* wk = (const float*)d_in[8];   const float* bk = (const float*)d_in[9];
    const float* wv = (const float*)d_in[10];  const float* bv = (const float*)d_in[11];
    const float* wm = (const float*)d_in[12];  const float* bm = (const float*)d_in[13];
    const float* w1 = (const float*)d_in[14];  const float* b1 = (const float*)d_in[15];
    const float* w2 = (const float*)d_in[16];  const float* b2 = (const float*)d_in[17];
    const float* wres = (const float*)d_in[18]; const float* bres = (const float*)d_in[19];

    float* ws   = (float*)d_ws;
    float* tT   = ws;                       // B*N*32      = 131072 f
    int*   knn  = (int*)(ws + 131072);      // B*M*32      = 131072 i
    float* fat  = ws + 262144;              // B*32*M      = 131072 f
    float* h1   = ws + 393216;              // B*64*M      = 262144 f
    float* mu   = ws + 655360;              // 128 f
    float* rstd = ws + 655488;              // 128 f

    float* feat_out = (float*)d_out;
    float* r_out    = feat_out + Bb * Dd * Mm;   // 131072

    transpose_kernel<<<128, 256, 0, stream>>>(target, tT);
    score_topk_kernel<<<512, 512, 0, stream>>>(source, tT, knn);
    attn_kernel<<<Bb * Mm, 256, 0, stream>>>(source, featinv, tT, knn,
                                             wq, bq, wk, bk, wv, bv, wm, bm,
                                             w1, b1, fat, h1);
    stats_kernel<<<Bb * 64, 256, 0, stream>>>(h1, mu, rstd);
    final_kernel<<<Bb * Mm / 8, 256, 0, stream>>>(source, featinv, fat, h1,
                                                  mu, rstd, w2, b2, wres, bres,
                                                  feat_out);
    r_kernel<<<Bb * Mm, 256, 0, stream>>>(source_eqv, target_eqv, perms, knn, r_out);
}

// Round 10
// 250.215 us; speedup vs baseline: 2.1691x; 2.1691x over previous
//
#include <hip/hip_runtime.h>
#include <hip/hip_bf16.h>
#include <math.h>

// Problem constants
#define Bb 2
#define Mm 2048
#define Nn 2048
#define Ff 8
#define Gg 60
#define Kk 32
#define Dd 32
#define Hh 4
#define DHh 8

// ---------------------------------------------------------------------------
// Kernel 1: transpose target (B,D,N,1) -> targetT (B,N,D) for coalesced dots
// ---------------------------------------------------------------------------
__global__ __launch_bounds__(256) void transpose_kernel(
    const float* __restrict__ target, float* __restrict__ tT)
{
    __shared__ float tile[32][33];
    int blk = blockIdx.x;          // 0..127  (B * N/32)
    int b = blk >> 6;
    int n0 = (blk & 63) << 5;
    int t = threadIdx.x;
    int col = t & 31;
    int rowb = t >> 5;             // 0..7
#pragma unroll
    for (int i = 0; i < 4; ++i) {
        int d = rowb + i * 8;
        tile[d][col] = target[(b * 32 + d) * 2048 + n0 + col];
    }
    __syncthreads();
#pragma unroll
    for (int i = 0; i < 4; ++i) {
        int r = rowb + i * 8;      // local n
        tT[(b * 2048 + n0 + r) * 32 + col] = tile[col][r];
    }
}

// ---------------------------------------------------------------------------
// Kernel 2 (v3 REVERT — measured 78 us, VGPR 60, zero scratch; v4's hoisted
// offsets + two-level selection spilled val[]/sr[] (692MB scratch writes,
// 366 us).  REGISTER CLIFF: do not add live state here without resource-
// usage verification.  8 waves (512 thr)/block, one m-row per wave; tT
// staged in 64-n chunks via global_load_lds, double-buffered, vmcnt(1).
// ---------------------------------------------------------------------------
__global__ __launch_bounds__(512, 4) void score_topk_kernel(
    const float* __restrict__ src, const float* __restrict__ tT,
    int* __restrict__ knn)
{
    __shared__ float4 tile[2][512];     // 2 x 8KB chunk buffers [row*8 + slot]
    __shared__ float s_sh[8][32];       // 8 source vectors for this block

    int blk = blockIdx.x;               // 512 blocks
    int b = blk >> 8;
    int m0 = (blk & 255) << 3;
    int t = threadIdx.x;                // 0..511
    int wave = t >> 6, lane = t & 63;

    // slot L = t; row r0 = L>>3 (0..63), swizzled col c0 = (L&7)^(r0&7)
    int r0 = t >> 3;
    int c0 = (t & 7) ^ (r0 & 7);

    const float4* tpan = (const float4*)(tT + b * 2048 * 32);  // 8 float4/row

    // ---- prologue: stage chunk 0 + load the 8 source vectors ----
    {
        const float4* gp = tpan + r0 * 8 + c0;       // chunk 0: n0 = 0
        __builtin_amdgcn_global_load_lds(
            (const __attribute__((address_space(1))) void*)gp,
            (__attribute__((address_space(3))) void*)&tile[0][wave * 64],
            16, 0, 0);
    }
    if (t < 256) {
        int d = t >> 3, mi = t & 7;
        s_sh[mi][d] = src[(b * 32 + d) * 2048 + m0 + mi];
    }
    __syncthreads();   // drains vmcnt(0): chunk 0 + s_sh ready

    float sr[32];
#pragma unroll
    for (int i = 0; i < 32; ++i) sr[i] = s_sh[wave][i];

    float val[32];
    int rbase = lane * 8;
    int sw = lane & 7;

    // ---- main loop: 32 chunks of 64 n ----
#pragma unroll
    for (int c = 0; c < 32; ++c) {
        int cur = c & 1;
        if (c < 31) {
            int n0 = (c + 1) << 6;
            const float4* gp = tpan + (n0 + r0) * 8 + c0;
            __builtin_amdgcn_global_load_lds(
                (const __attribute__((address_space(1))) void*)gp,
                (__attribute__((address_space(3))) void*)&tile[cur ^ 1][wave * 64],
                16, 0, 0);
            asm volatile("s_waitcnt vmcnt(1)" ::: "memory");  // chunk c landed
        } else {
            asm volatile("s_waitcnt vmcnt(0)" ::: "memory");
        }
        __builtin_amdgcn_s_barrier();     // all waves' chunk-c stores landed
        asm volatile("" ::: "memory");    // fence: no load hoisting above barrier

        const float4* tb = &tile[cur][0];
        float a0 = 0.f;
#pragma unroll
        for (int q = 0; q < 8; ++q) {
            float4 f = tb[rbase + (q ^ sw)];
            a0 += f.x * sr[4 * q] + f.y * sr[4 * q + 1] +
                  f.z * sr[4 * q + 2] + f.w * sr[4 * q + 3];
        }
        val[c] = a0;
        asm volatile("s_waitcnt lgkmcnt(0)" ::: "memory");  // reads of buf done
        __builtin_amdgcn_s_barrier();     // before next stage overwrites buf
        asm volatile("" ::: "memory");
    }

    // ---- exact top-32 selection (scores val[j] for n = j*64 + lane) ----
    {
        float bestv = -INFINITY;
        int besti = 0x7FFFFFFF;
#pragma unroll
        for (int j = 0; j < 32; ++j) {
            if (val[j] > bestv) { bestv = val[j]; besti = lane + (j << 6); }
        }
        unsigned mask = 0u;
        int m = m0 + wave;
        int* kout = knn + (b * 2048 + m) * 32;
        for (int k = 0; k < 32; ++k) {
            float v = bestv;
            int i = besti;
#pragma unroll
            for (int off = 32; off > 0; off >>= 1) {
                float ov = __shfl_xor(v, off);
                int oi = __shfl_xor(i, off);
                if (ov > v || (ov == v && oi < i)) { v = ov; i = oi; }
            }
            if (lane == 0) kout[k] = i;
            if ((i & 63) == lane) {               // owner lane: remove & rescan
                mask |= 1u << (i >> 6);
                bestv = -INFINITY;
                besti = 0x7FFFFFFF;
#pragma unroll
                for (int j = 0; j < 32; ++j) {
                    if (!((mask >> j) & 1u) && val[j] > bestv) {
                        bestv = val[j];
                        besti = lane + (j << 6);
                    }
                }
            }
        }
    }
}

// ---------------------------------------------------------------------------
// Kernel 3: fused gather + QKV + attention + feat_attn + MLP layer 1.
// One block (256 thr) per (b,m). Head h owns channels d with d%4==h.
// ---------------------------------------------------------------------------
__global__ __launch_bounds__(256) void attn_kernel(
    const float* __restrict__ src, const float* __restrict__ featinv,
    const float* __restrict__ tT, const int* __restrict__ knn,
    const float* __restrict__ wq, const float* __restrict__ bq,
    const float* __restrict__ wk, const float* __restrict__ bk,
    const float* __restrict__ wv, const float* __restrict__ bv,
    const float* __restrict__ wm, const float* __restrict__ bm,
    const float* __restrict__ w1, const float* __restrict__ b1,
    float* __restrict__ fat, float* __restrict__ h1out)
{
    __shared__ float kf[32][33], kk[32][33], vv[32][33];
    __shared__ float wks[1024], wvs[1024];       // transposed: [i*32+o]
    __shared__ float s[32], qv[32], xv[32];
    __shared__ float scs[4][32], prob[4][32];
    __shared__ float cat[96];
    __shared__ int idx[32];

    int blk = blockIdx.x;
    int b = blk >> 11;
    int m = blk & 2047;
    int t = threadIdx.x;
    int d = t & 31, kn0 = t >> 5;

    if (t < 32) {
        s[t] = src[(b * 32 + t) * 2048 + m];
        idx[t] = knn[(b * 2048 + m) * 32 + t];
    }
#pragma unroll
    for (int r = 0; r < 4; ++r) {
        int w = t + 256 * r;
        wks[w] = wk[(w & 31) * 32 + (w >> 5)];   // wks[i*32+o] = wk[o][i]
        wvs[w] = wv[(w & 31) * 32 + (w >> 5)];
    }
    __syncthreads();

    // gather 32 neighbor features (coalesced 128B per neighbor)
#pragma unroll
    for (int i = 0; i < 4; ++i) {
        int kn = kn0 + i * 8;
        kf[kn][d] = tT[(b * 2048 + idx[kn]) * 32 + d];
    }
    if (t < 32) {
        float acc = bq[t];
#pragma unroll
        for (int i = 0; i < 32; ++i) acc += wq[t * 32 + i] * s[i];
        qv[t] = acc;
    }
    __syncthreads();

    // K,V projections: thread (o=d, kn = kn0+8i)
#pragma unroll
    for (int i = 0; i < 4; ++i) {
        int kn = kn0 + i * 8;
        float ak = bk[d], av = bv[d];
#pragma unroll
        for (int j = 0; j < 32; ++j) {
            float f = kf[kn][j];
            ak += wks[j * 32 + d] * f;
            av += wvs[j * 32 + d] * f;
        }
        kk[kn][d] = ak;
        vv[kn][d] = av;
    }
    __syncthreads();

    // attention scores: head h uses channels dh*4+h
    if (t < 128) {
        int kn = t >> 2, h = t & 3;
        float acc = 0.f;
#pragma unroll
        for (int dh = 0; dh < 8; ++dh) acc += qv[dh * 4 + h] * kk[kn][dh * 4 + h];
        scs[h][kn] = acc * 0.35355339059327373f;  // 1/sqrt(8)
    }
    __syncthreads();
    // wave-parallel softmax: t = h*32 + kn, shfl reductions within 32-lane groups
    if (t < 128) {
        int h = t >> 5, kn = t & 31;
        float sc = scs[h][kn];
        float mx = sc;
#pragma unroll
        for (int off = 16; off > 0; off >>= 1) mx = fmaxf(mx, __shfl_xor(mx, off));
        float e = expf(sc - mx);
        float sum = e;
#pragma unroll
        for (int off = 16; off > 0; off >>= 1) sum += __shfl_xor(sum, off);
        prob[h][kn] = e / sum;
    }
    __syncthreads();
    if (t < 32) {
        int h = t & 3;
        float acc = 0.f;
#pragma unroll
        for (int kn = 0; kn < 32; ++kn) acc += prob[h][kn] * vv[kn][t];
        xv[t] = acc;
    }
    __syncthreads();
    if (t < 32) {
        float acc = bm[t];
#pragma unroll
        for (int i = 0; i < 32; ++i) acc += wm[t * 32 + i] * xv[i];
        fat[(b * 32 + t) * 2048 + m] = acc;
        cat[t] = featinv[(b * 32 + t) * 2048 + m];
        cat[32 + t] = s[t];
        cat[64 + t] = acc;
    }
    __syncthreads();
    // MLP layer 1 (96 -> 64); instance-norm stats need global pass -> store
    if (t < 64) {
        float acc = b1[t];
#pragma unroll
        for (int i = 0; i < 96; ++i) acc += w1[t * 96 + i] * cat[i];
        h1out[(b * 64 + t) * 2048 + m] = acc;
    }
}

// ---------------------------------------------------------------------------
// Kernel 4: instance-norm stats per (b, channel) over M
// ---------------------------------------------------------------------------
__global__ __launch_bounds__(256) void stats_kernel(
    const float* __restrict__ h1, float* __restrict__ mu, float* __restrict__ rstd)
{
    __shared__ float rs[256], rq[256];
    int bc = blockIdx.x;
    int t = threadIdx.x;
    const float* row = h1 + bc * 2048;
    float sum = 0.f, sq = 0.f;
#pragma unroll
    for (int r = 0; r < 8; ++r) {
        float v = row[t + 256 * r];
        sum += v;
        sq += v * v;
    }
    rs[t] = sum; rq[t] = sq;
    __syncthreads();
    for (int off = 128; off > 0; off >>= 1) {
        if (t < off) { rs[t] += rs[t + off]; rq[t] += rq[t + off]; }
        __syncthreads();
    }
    if (t == 0) {
        float m_ = rs[0] * (1.f / 2048.f);
        float var = rq[0] * (1.f / 2048.f) - m_ * m_;
        mu[bc] = m_;
        rstd[bc] = rsqrtf(var + 1e-5f);
    }
}

// ---------------------------------------------------------------------------
// Kernel 5: norm + ReLU + (w2 @ h + wres @ cat) epilogue -> feat_out
// One block handles 8 m values; thread = (m-sub g, out channel o).
// ---------------------------------------------------------------------------
__global__ __launch_bounds__(256) void final_kernel(
    const float* __restrict__ src, const float* __restrict__ featinv,
    const float* __restrict__ fat, const float* __restrict__ h1,
    const float* __restrict__ mu, const float* __restrict__ rstd,
    const float* __restrict__ w2, const float* __restrict__ b2,
    const float* __restrict__ wres, const float* __restrict__ bres,
    float* __restrict__ out)
{
    __shared__ float hbuf[64][8];
    __shared__ float catbuf[96][8];
    __shared__ float w2s[2048];    // [c*32+o]
    __shared__ float wress[3072];  // [i*32+o]
    int blk = blockIdx.x;
    int b = blk >> 8;
    int m0 = (blk & 255) << 3;
    int t = threadIdx.x;
#pragma unroll
    for (int r = 0; r < 8; ++r) {
        int w = t + 256 * r;
        w2s[w] = w2[(w & 31) * 64 + (w >> 5)];
    }
#pragma unroll
    for (int r = 0; r < 12; ++r) {
        int w = t + 256 * r;
        wress[w] = wres[(w & 31) * 96 + (w >> 5)];
    }
#pragma unroll
    for (int r = 0; r < 2; ++r) {
        int i = t + 256 * r;
        int c = i >> 3, mm = i & 7;
        int bc = b * 64 + c;
        float v = h1[(b * 64 + c) * 2048 + m0 + mm];
        v = (v - mu[bc]) * rstd[bc];
        hbuf[c][mm] = fmaxf(v, 0.f);
    }
#pragma unroll
    for (int r = 0; r < 3; ++r) {
        int i = t + 256 * r;
        int c = i >> 3, mm = i & 7;
        float v;
        if (c < 32)      v = featinv[(b * 32 + c) * 2048 + m0 + mm];
        else if (c < 64) v = src[(b * 32 + (c - 32)) * 2048 + m0 + mm];
        else             v = fat[(b * 32 + (c - 64)) * 2048 + m0 + mm];
        catbuf[c][mm] = v;
    }
    __syncthreads();
    int o = t & 31, g = t >> 5;
    float acc = b2[o] + bres[o];
#pragma unroll
    for (int c = 0; c < 64; ++c) acc += w2s[c * 32 + o] * hbuf[c][g];
#pragma unroll
    for (int i = 0; i < 96; ++i) acc += wress[i * 32 + o] * catbuf[i][g];
    out[(b * 32 + o) * 2048 + m0 + g] = acc;
}

// ---------------------------------------------------------------------------
// Kernel 6 (v2): R_indicator. One block per (b,m).
// R[h2] = sum_{f,g} source_eqv[b,f,m,perms[g*60+h2]] * target_eqv[b,f,nn,g]
// LDS layouts transposed to [g][f] float4 pairs: inner gather is 4x
// ds_read_b128 instead of 16x scalar reads.
// ---------------------------------------------------------------------------
__global__ __launch_bounds__(256) void r_kernel(
    const float* __restrict__ source_eqv, const float* __restrict__ target_eqv,
    const int* __restrict__ perms, const int* __restrict__ knn,
    float* __restrict__ out)
{
    __shared__ float4 seT[60][2];   // [p][f/4]
    __shared__ float4 tkT[60][2];   // [g][f/4]
    __shared__ int pl[3600];
    __shared__ float part[4][60];
    int blk = blockIdx.x;
    int b = blk >> 11;
    int m = blk & 2047;
    int t = threadIdx.x;
    int nn = knn[(b * 2048 + m) * 32];   // top-1 index
#pragma unroll
    for (int r = 0; r < 2; ++r) {
        int i = t + 256 * r;
        if (i < 480) {
            int f = i / 60, g = i - f * 60;
            ((float*)&tkT[g][0])[f] = target_eqv[((b * 8 + f) * 2048 + nn) * 60 + g];
            ((float*)&seT[g][0])[f] = source_eqv[((b * 8 + f) * 2048 + m) * 60 + g];
        }
    }
#pragma unroll
    for (int r = 0; r < 15; ++r) {
        int i = t + 256 * r;
        if (i < 3600) pl[i] = perms[i];
    }
    __syncthreads();
    if (t < 240) {
        int h2 = t % 60, quarter = t / 60;
        float acc = 0.f;
        for (int g = quarter * 15; g < quarter * 15 + 15; ++g) {
            int p = pl[g * 60 + h2];
            float4 s0 = seT[p][0], s1 = seT[p][1];
            float4 k0 = tkT[g][0], k1 = tkT[g][1];
            acc += s0.x * k0.x + s0.y * k0.y + s0.z * k0.z + s0.w * k0.w
                 + s1.x * k1.x + s1.y * k1.y + s1.z * k1.z + s1.w * k1.w;
        }
        part[quarter][h2] = acc;
    }
    __syncthreads();
    if (t < 60)
        out[(b * 60 + t) * 2048 + m] =
            part[0][t] + part[1][t] + part[2][t] + part[3][t];
}

// ---------------------------------------------------------------------------
extern "C" void kernel_launch(void* const* d_in, const int* in_sizes, int n_in,
                              void* d_out, int out_size, void* d_ws, size_t ws_size,
                              hipStream_t stream)
{
    const float* source     = (const float*)d_in[0];
    const float* target     = (const float*)d_in[1];
    const float* source_eqv = (const float*)d_in[2];
    const float* target_eqv = (const float*)d_in[3];
    const float* featinv    = (const float*)d_in[4];
    const int*   perms      = (const int*)d_in[5];
    const float* wq = (const float*)d_in[6];   const float* bq = (const float*)d_in[7];
    const float* wk = (const float*)d_in[8];   const float* bk = (const float*)d_in[9];
    const float* wv = (const float*)d_in[10];  const float* bv = (const float*)d_in[11];
    const float* wm = (const float*)d_in[12];  const float* bm = (const float*)d_in[13];
    const float* w1 = (const float*)d_in[14];  const float* b1 = (const float*)d_in[15];
    const float* w2 = (const float*)d_in[16];  const float* b2 = (const float*)d_in[17];
    const float* wres = (const float*)d_in[18]; const float* bres = (const float*)d_in[19];

    float* ws   = (float*)d_ws;
    float* tT   = ws;                       // B*N*32      = 131072 f
    int*   knn  = (int*)(ws + 131072);      // B*M*32      = 131072 i
    float* fat  = ws + 262144;              // B*32*M      = 131072 f
    float* h1   = ws + 393216;              // B*64*M      = 262144 f
    float* mu   = ws + 655360;              // 128 f
    float* rstd = ws + 655488;              // 128 f

    float* feat_out = (float*)d_out;
    float* r_out    = feat_out + Bb * Dd * Mm;   // 131072

    transpose_kernel<<<128, 256, 0, stream>>>(target, tT);
    score_topk_kernel<<<512, 512, 0, stream>>>(source, tT, knn);
    attn_kernel<<<Bb * Mm, 256, 0, stream>>>(source, featinv, tT, knn,
                                             wq, bq, wk, bk, wv, bv, wm, bm,
                                             w1, b1, fat, h1);
    stats_kernel<<<Bb * 64, 256, 0, stream>>>(h1, mu, rstd);
    final_kernel<<<Bb * Mm / 8, 256, 0, stream>>>(source, featinv, fat, h1,
                                                  mu, rstd, w2, b2, wres, bres,
                                                  feat_out);
    r_kernel<<<Bb * Mm, 256, 0, stream>>>(source_eqv, target_eqv, perms, knn, r_out);
}